// Round 16
// baseline (392.005 us; speedup 1.0000x reference)
//
#include <hip/hip_runtime.h>
#include <hip/hip_bf16.h>

#define DEVINL __device__ __forceinline__

typedef __attribute__((ext_vector_type(8))) short bf16x8;
typedef __attribute__((ext_vector_type(4))) float f32x4;

static constexpr int SS = 12288;   // S = NKV
static constexpr float QKS = 0.17677669529663687f;  // 1/sqrt(32), folded into Wa_q

DEVINL f32x4 f32x4_zero() { f32x4 z; z[0]=0.f; z[1]=0.f; z[2]=0.f; z[3]=0.f; return z; }
DEVINL f32x4 mfma16(bf16x8 a, bf16x8 b, f32x4 c) {
  return __builtin_amdgcn_mfma_f32_16x16x32_bf16(a, b, c, 0, 0, 0);
}
DEVINL unsigned short f2bf(float f) {   // prep kernels only
  __hip_bfloat16 h = __float2bfloat16(f);
  return __builtin_bit_cast(unsigned short, h);
}
DEVINL float bf2f(unsigned short u) {
  unsigned v = ((unsigned)u) << 16;
  return __builtin_bit_cast(float, v);
}
DEVINL unsigned cvt_pk_bf16(float lo_, float hi_) {  // [15:0]=lo_, [31:16]=hi_
  unsigned r;
  asm volatile("v_cvt_pk_bf16_f32 %0, %1, %2" : "=v"(r) : "v"(lo_), "v"(hi_));
  return r;
}
// 8-way XOR-swizzled element offset into a [16][128] bf16 LDS tile (R5/R9-proven)
DEVINL int swz(int r, int c) {
  return (r << 7) + ((((c >> 3) ^ (r & 7))) << 3) + (c & 7);
}
DEVINL void wave_sync() {
  asm volatile("s_waitcnt lgkmcnt(0)" ::: "memory");
  __builtin_amdgcn_sched_barrier(0);
}
DEVINL float gelu_f(float x) {  // tanh-approximate gelu (jax default)
  float u = 0.7978845608028654f * (x + 0.044715f * x * x * x);
  float t = 1.0f - 2.0f / (__expf(2.0f * u) + 1.0f);
  return 0.5f * x * (1.0f + t);
}

// ---------------------------------------------------------------------------
// Kernel 0: repack six 128x128 fp32 weights into bf16 MFMA A-fragment order
// (A = W^T). slice j = mat*4+kt; elem (j, mt, l, i) holds
// W[kt*32+(l>>4)*8+i][mt*16+(l&15)]  (Wa_q pre-scaled by QKS).
// ---------------------------------------------------------------------------
__global__ void prep_weights(const float* __restrict__ w0, const float* __restrict__ w1,
                             const float* __restrict__ w2, const float* __restrict__ w3,
                             const float* __restrict__ w4, const float* __restrict__ w5,
                             unsigned short* __restrict__ wfrag) {
  int gid = blockIdx.x * 256 + threadIdx.x;   // < 98304
  int i  = gid & 7;
  int l  = (gid >> 3) & 63;
  int mt = (gid >> 9) & 7;
  int kt = (gid >> 12) & 3;
  int mat = gid >> 14;
  const float* W = (mat == 0) ? w0 : (mat == 1) ? w1 : (mat == 2) ? w2
                 : (mat == 3) ? w3 : (mat == 4) ? w4 : w5;
  int k = kt * 32 + (l >> 4) * 8 + i;
  int c = mt * 16 + (l & 15);
  float v = W[k * 128 + c];
  if (mat == 1) v *= QKS;
  wfrag[gid] = f2bf(v);
}

// ---------------------------------------------------------------------------
// Kernel 1: kv = LN(x_kv) @ Wkv + bkv -> bf16 workspace [24576][256]  (R9)
// ---------------------------------------------------------------------------
__global__ __launch_bounds__(256) void kv_proj(
    const float* __restrict__ xkv, const float* __restrict__ lns,
    const float* __restrict__ lnb, const float* __restrict__ Wkv,
    const float* __restrict__ bkv, unsigned short* __restrict__ kvout) {
  __shared__ float y[16][132];
  const int tid = threadIdx.x;
  const size_t rb = (size_t)blockIdx.x * 16;
  {
    int r = tid >> 4, p = tid & 15;
    const float* xr = xkv + (rb + r) * 128 + p * 8;
    float v[8];
    float sum = 0.f, sq = 0.f;
#pragma unroll
    for (int i = 0; i < 2; ++i) {
      float4 q4 = *(const float4*)(xr + i * 4);
      v[i*4+0]=q4.x; v[i*4+1]=q4.y; v[i*4+2]=q4.z; v[i*4+3]=q4.w;
      sum += q4.x + q4.y + q4.z + q4.w;
      sq  += q4.x*q4.x + q4.y*q4.y + q4.z*q4.z + q4.w*q4.w;
    }
    sum += __shfl_xor(sum, 1, 16); sum += __shfl_xor(sum, 2, 16);
    sum += __shfl_xor(sum, 4, 16); sum += __shfl_xor(sum, 8, 16);
    sq  += __shfl_xor(sq, 1, 16);  sq  += __shfl_xor(sq, 2, 16);
    sq  += __shfl_xor(sq, 4, 16);  sq  += __shfl_xor(sq, 8, 16);
    float mu = sum * (1.0f/128.f);
    float rs = rsqrtf(sq * (1.0f/128.f) - mu*mu + 1e-5f);
#pragma unroll
    for (int i = 0; i < 8; ++i) {
      int c = p * 8 + i;
      y[r][c] = (v[i] - mu) * rs * lns[c] + lnb[c];
    }
  }
  __syncthreads();
  const int c2 = tid;
  float acc[16];
#pragma unroll
  for (int r = 0; r < 16; ++r) acc[r] = 0.f;
  for (int c = 0; c < 128; c += 4) {
    float w0 = Wkv[(c+0)*256 + c2];
    float w1 = Wkv[(c+1)*256 + c2];
    float w2 = Wkv[(c+2)*256 + c2];
    float w3 = Wkv[(c+3)*256 + c2];
#pragma unroll
    for (int r = 0; r < 16; ++r) {
      float4 yv = *(const float4*)&y[r][c];
      acc[r] += yv.x*w0 + yv.y*w1 + yv.z*w2 + yv.w*w3;
    }
  }
  float bb = bkv[c2];
#pragma unroll
  for (int r = 0; r < 16; ++r)
    kvout[(rb + r) * 256 + c2] = f2bf(acc[r] + bb);
}

// ---------------------------------------------------------------------------
// mmReg: per-wave flipped 16x128 @ 128x128 with weights read DIRECTLY from
// L2-hot global wfrag into a register ping-pong (kt+1's 8 frags issued before
// kt's MFMAs). No LDS weight staging, no barriers. All math R9-verbatim.
// wmat = wfrag + mat*16384; frag addr = wmat + kt*4096 + (mt*64+l)*8.
// MODE 0: (+bias) -> X. MODE 1: +bias, gelu -> X.
// MODE 2: x2 = xq + gamma*(acc+bias) -> packed bf16 regs x2p[16].
// MODE 3: m = acc+bias; out = unpack(x2p) + gmlp*m -> global float4.
// ---------------------------------------------------------------------------
template <int MODE>
DEVINL void mmReg(unsigned short* X, const unsigned short* __restrict__ wmat,
                  const float* __restrict__ bias,
                  const float* __restrict__ xqw, const float* __restrict__ gamma,
                  unsigned* x2p, const float* __restrict__ gmlp,
                  float* __restrict__ outw, int lo, int g, int l) {
  f32x4 acc[8];
#pragma unroll
  for (int mt = 0; mt < 8; ++mt) acc[mt] = f32x4_zero();

  const unsigned short* wl = wmat + l * 8;   // lane base
  bf16x8 w[2][8];
#pragma unroll
  for (int mt = 0; mt < 8; ++mt)             // preload kt = 0
    w[0][mt] = *(const bf16x8*)(wl + mt * 512);

#pragma unroll
  for (int kt = 0; kt < 4; ++kt) {
    if (kt < 3) {                            // prefetch kt+1 before MFMAs
#pragma unroll
      for (int mt = 0; mt < 8; ++mt)
        w[(kt + 1) & 1][mt] = *(const bf16x8*)(wl + (kt + 1) * 4096 + mt * 512);
    }
    bf16x8 b = *(const bf16x8*)(X + swz(lo, kt * 32 + g * 8));
#pragma unroll
    for (int mt = 0; mt < 8; ++mt)
      acc[mt] = mfma16(w[kt & 1][mt], b, acc[mt]);
  }

#pragma unroll
  for (int mt = 0; mt < 8; ++mt) {
    int c0 = mt * 16 + g * 4;
    float v0 = acc[mt][0], v1 = acc[mt][1], v2 = acc[mt][2], v3 = acc[mt][3];
    if (bias) {
      float4 b4 = *(const float4*)(bias + c0);
      v0 += b4.x; v1 += b4.y; v2 += b4.z; v3 += b4.w;
    }
    if (MODE == 1) { v0 = gelu_f(v0); v1 = gelu_f(v1); v2 = gelu_f(v2); v3 = gelu_f(v3); }
    if (MODE == 2) {
      float4 x4 = *(const float4*)(xqw + lo * 128 + c0);
      float4 g4 = *(const float4*)(gamma + c0);
      v0 = x4.x + g4.x * v0; v1 = x4.y + g4.y * v1;
      v2 = x4.z + g4.z * v2; v3 = x4.w + g4.w * v3;
      x2p[2 * mt]     = cvt_pk_bf16(v0, v1);
      x2p[2 * mt + 1] = cvt_pk_bf16(v2, v3);
    } else if (MODE == 3) {
      float4 p4 = *(const float4*)(gmlp + c0);
      unsigned xa = x2p[2 * mt], xb = x2p[2 * mt + 1];
      float4 o;
      o.x = bf2f((unsigned short)(xa & 0xffff))  + p4.x * v0;
      o.y = bf2f((unsigned short)(xa >> 16))     + p4.y * v1;
      o.z = bf2f((unsigned short)(xb & 0xffff))  + p4.z * v2;
      o.w = bf2f((unsigned short)(xb >> 16))     + p4.w * v3;
      *(float4*)(outw + lo * 128 + c0) = o;
    } else {
      uint2 w2;
      w2.x = cvt_pk_bf16(v0, v1);
      w2.y = cvt_pk_bf16(v2, v3);
      *(uint2*)(X + swz(lo, c0)) = w2;
    }
  }
}

// ---------------------------------------------------------------------------
// Kernel 2: fused main, fully barrier-free. Block = 4 independent waves, each
// owning 1 s-unit; weights register-prefetched from L2-hot wfrag; per-su LDS
// 6.25 KB (X | K), 25.6 KB/block. All per-su math R9/R15-verbatim.
// ---------------------------------------------------------------------------
__global__ __launch_bounds__(256, 3) void fused_main(
    const float* __restrict__ xq, const int* __restrict__ nh_idx,
    const unsigned char* __restrict__ nh_mask,
    const unsigned short* __restrict__ wfrag,
    const unsigned short* __restrict__ kvws,
    const float* __restrict__ ln_q_s, const float* __restrict__ ln_q_b,
    const float* __restrict__ bq, const float* __restrict__ b_out,
    const float* __restrict__ gamma, const float* __restrict__ ln_m_s,
    const float* __restrict__ ln_m_b, const float* __restrict__ bm,
    const float* __restrict__ b1, const float* __restrict__ b2,
    const float* __restrict__ gmlp, float* __restrict__ out) {
  __shared__ __align__(16) unsigned short SU[4][3200];   // per-su X 2048 | K 1152

  const int tid = threadIdx.x, l = tid & 63, wv = tid >> 6;
  const int lo = l & 15, g = l >> 4;
  // T1: XCD-aware bijective block swizzle (gridDim.x = 6144, 6144 % 8 == 0)
  const int nwg = gridDim.x;
  const int cpx = nwg >> 3;
  const int bid = (blockIdx.x & 7) * cpx + (blockIdx.x >> 3);
  const int su = bid * 4 + wv;                  // < 24576
  const int t = su / SS, s = su - t * SS;
  const float* xqw = xq + (size_t)su * 2048;
  float* outw = out + (size_t)su * 2048;
  unsigned short* X = SU[wv];             // activations [16][128] swz / V overlay
  unsigned short* K = SU[wv] + 2048;      // K rows [9][128] swz

  // ---- P0: score bias; kv gather (K lands now, V held in regs)
  float sbias[4];
#pragma unroll
  for (int e = 0; e < 4; ++e) {
    int n = g * 4 + e;
    sbias[e] = (n < 9) ? (nh_mask[s * 9 + n] ? 0.0f : -1e9f) : -1e9f;
  }
  uint4 gr[5];
  {
#pragma unroll
    for (int i = 0; i < 5; ++i) {
      int idx = i * 64 + l;               // 288 = 9 rows x 32 chunks of 16 B
      if (idx < 288) {
        int n = idx >> 5, ch = idx & 31;
        int jrow = nh_idx[s * 9 + n];
        gr[i] = *(const uint4*)(kvws + ((size_t)(t * SS + jrow)) * 256 + ch * 8);
      }
    }
#pragma unroll
    for (int i = 0; i < 5; ++i) {         // land K half immediately
      int idx = i * 64 + l;
      if (idx < 288 && (idx & 31) < 16) {
        int n = idx >> 5, ch = idx & 31;
        *(uint4*)(K + n * 128 + ((ch ^ (n & 7)) << 3)) = gr[i];
      }
    }
  }

  // ---- P1: LN1 -> X (flip layout: lane owns row lo, channels mt*16+g*4..+3)
  {
    float4 xv[8];
    float sum = 0.f, sq = 0.f;
#pragma unroll
    for (int mt = 0; mt < 8; ++mt) {
      xv[mt] = *(const float4*)(xqw + lo * 128 + mt * 16 + g * 4);
      sum += xv[mt].x + xv[mt].y + xv[mt].z + xv[mt].w;
      sq  += xv[mt].x*xv[mt].x + xv[mt].y*xv[mt].y + xv[mt].z*xv[mt].z + xv[mt].w*xv[mt].w;
    }
    sum += __shfl_xor(sum, 16); sum += __shfl_xor(sum, 32);
    sq  += __shfl_xor(sq, 16);  sq  += __shfl_xor(sq, 32);
    float mu = sum * (1.0f/128.f);
    float rs = rsqrtf(sq * (1.0f/128.f) - mu*mu + 1e-5f);
#pragma unroll
    for (int mt = 0; mt < 8; ++mt) {
      int c0 = mt * 16 + g * 4;
      float4 s4 = *(const float4*)(ln_q_s + c0);
      float4 b4 = *(const float4*)(ln_q_b + c0);
      uint2 w2;
      w2.x = cvt_pk_bf16((xv[mt].x - mu) * rs * s4.x + b4.x,
                         (xv[mt].y - mu) * rs * s4.y + b4.y);
      w2.y = cvt_pk_bf16((xv[mt].z - mu) * rs * s4.z + b4.z,
                         (xv[mt].w - mu) * rs * s4.w + b4.w);
      *(uint2*)(X + swz(lo, c0)) = w2;
    }
  }
  wave_sync();

  unsigned x2p[16];

  // q  = y1 @ Wq + bq            (mat 0)
  mmReg<0>(X, wfrag + 0 * 16384, bq, nullptr, nullptr, nullptr, nullptr, nullptr, lo, g, l);
  wave_sync();
  // qh = q @ (Wa_q * QKS)        (mat 1)
  mmReg<0>(X, wfrag + 1 * 16384, nullptr, nullptr, nullptr, nullptr, nullptr, nullptr, lo, g, l);
  wave_sync();

  // ---- attention (wave-local, MFMA; R9-verbatim) + T5 setprio
  {
    const int krow = (lo > 8) ? 8 : lo;   // clamp; garbage rows killed by sbias
    f32x4 st[4];
    __builtin_amdgcn_s_setprio(1);
#pragma unroll
    for (int h = 0; h < 4; ++h) {
      bf16x8 ka = *(const bf16x8*)(K + swz(krow, h * 32 + g * 8));  // A = K
      bf16x8 qb = *(const bf16x8*)(X + swz(lo,   h * 32 + g * 8));  // B = qh
      st[h] = mfma16(ka, qb, f32x4_zero());                         // St[n][q]
    }
    __builtin_amdgcn_s_setprio(0);
    wave_sync();   // qh reads retired -> X reusable for V
    // land V interleaved into X: [8 nt][8 npair][16 d][2] (stale slots finite)
#pragma unroll
    for (int i = 0; i < 5; ++i) {
      int idx = i * 64 + l;
      if (idx < 288 && (idx & 31) >= 16) {
        int n = idx >> 5, d0 = ((idx & 31) - 16) * 8;
        int nt = d0 >> 4;
        int base = nt * 256 + (n >> 1) * 32 + (d0 & 15) * 2 + (n & 1);
        const unsigned short* u = (const unsigned short*)&gr[i];
#pragma unroll
        for (int dd = 0; dd < 8; ++dd) X[base + dd * 2] = u[dd];
      }
    }
    // softmax over n (in-lane e + shfl over g) and P A-frag assembly
    bf16x8 pfrag[4];
#pragma unroll
    for (int h = 0; h < 4; ++h) {
      float p0 = st[h][0] + sbias[0], p1 = st[h][1] + sbias[1];
      float p2 = st[h][2] + sbias[2], p3 = st[h][3] + sbias[3];
      float m = fmaxf(fmaxf(p0, p1), fmaxf(p2, p3));
      m = fmaxf(m, __shfl_xor(m, 16)); m = fmaxf(m, __shfl_xor(m, 32));
      p0 = __expf(p0 - m); p1 = __expf(p1 - m);
      p2 = __expf(p2 - m); p3 = __expf(p3 - m);
      float ss = p0 + p1 + p2 + p3;
      ss += __shfl_xor(ss, 16); ss += __shfl_xor(ss, 32);
      float inv = 1.0f / ss;
      p0 *= inv; p1 *= inv; p2 *= inv; p3 *= inv;
      // lane needs P[q=lo][n=g*8+i]; own lane holds P[n=g*4+e][q=lo]
      float b0 = __shfl_xor(p0, 16), b1 = __shfl_xor(p1, 16),
            b2_ = __shfl_xor(p2, 16), b3 = __shfl_xor(p3, 16);
      float c0_ = __shfl_xor(p0, 32), c1 = __shfl_xor(p1, 32),
            c2 = __shfl_xor(p2, 32), c3 = __shfl_xor(p3, 32);
      float d0_ = __shfl_xor(p0, 48), d1 = __shfl_xor(p1, 48),
            d2 = __shfl_xor(p2, 48), d3 = __shfl_xor(p3, 48);
      float L0 = (g == 0) ? p0 : (g == 1) ? d0_ : 0.f;
      float L1 = (g == 0) ? p1 : (g == 1) ? d1 : 0.f;
      float L2 = (g == 0) ? p2 : (g == 1) ? d2 : 0.f;
      float L3 = (g == 0) ? p3 : (g == 1) ? d3 : 0.f;
      float H0 = (g == 0) ? b0 : (g == 1) ? c0_ : 0.f;
      float H1 = (g == 0) ? b1 : (g == 1) ? c1 : 0.f;
      float H2 = (g == 0) ? b2_ : (g == 1) ? c2 : 0.f;
      float H3 = (g == 0) ? b3 : (g == 1) ? c3 : 0.f;
      uint4 pu;
      pu.x = cvt_pk_bf16(L0, L1); pu.y = cvt_pk_bf16(L2, L3);
      pu.z = cvt_pk_bf16(H0, H1); pu.w = cvt_pk_bf16(H2, H3);
      pfrag[h] = __builtin_bit_cast(bf16x8, pu);
    }
    wave_sync();   // V writes landed
    // PV: out[q][d] = P @ V; B-frag = 4x ds_read_b32 (g<2 hold n=0..15)
    f32x4 oacc[8];
    __builtin_amdgcn_s_setprio(1);
#pragma unroll
    for (int nt = 0; nt < 8; ++nt) {
      unsigned vw0 = 0, vw1 = 0, vw2 = 0, vw3 = 0;
      if (g < 2) {
        const unsigned short* vb = X + nt * 256 + g * 128 + lo * 2;
        vw0 = *(const unsigned*)(vb);
        vw1 = *(const unsigned*)(vb + 32);
        vw2 = *(const unsigned*)(vb + 64);
        vw3 = *(const unsigned*)(vb + 96);
      }
      uint4 vu; vu.x = vw0; vu.y = vw1; vu.z = vw2; vu.w = vw3;
      bf16x8 vfrag = __builtin_bit_cast(bf16x8, vu);
      oacc[nt] = mfma16(pfrag[nt >> 1], vfrag, f32x4_zero());
    }
    __builtin_amdgcn_s_setprio(0);
    wave_sync();   // V reads done -> overwrite X with ao (full coverage)
#pragma unroll
    for (int nt = 0; nt < 8; ++nt)
#pragma unroll
      for (int e = 0; e < 4; ++e)
        X[swz(g * 4 + e, nt * 16 + lo)] = (unsigned short)(cvt_pk_bf16(oacc[nt][e], 0.f) & 0xffff);
    wave_sync();
  }

  // x2 = xq + gamma*(ao @ W_out + b_out) -> x2p regs   (mat 2)
  mmReg<2>(X, wfrag + 2 * 16384, b_out, xqw, gamma, x2p, nullptr, nullptr, lo, g, l);

  // ---- LN2 from x2p -> y2 -> X (lane owns full row lo)
  {
    float sum = 0.f, sq = 0.f;
#pragma unroll
    for (int mt = 0; mt < 8; ++mt) {
      unsigned xa = x2p[2*mt], xb = x2p[2*mt+1];
      float v0 = bf2f((unsigned short)(xa & 0xffff));
      float v1 = bf2f((unsigned short)(xa >> 16));
      float v2 = bf2f((unsigned short)(xb & 0xffff));
      float v3 = bf2f((unsigned short)(xb >> 16));
      sum += v0 + v1 + v2 + v3;
      sq  += v0*v0 + v1*v1 + v2*v2 + v3*v3;
    }
    sum += __shfl_xor(sum, 16); sum += __shfl_xor(sum, 32);
    sq  += __shfl_xor(sq, 16);  sq  += __shfl_xor(sq, 32);
    float mu = sum * (1.0f/128.f);
    float rs = rsqrtf(sq * (1.0f/128.f) - mu*mu + 1e-5f);
#pragma unroll
    for (int mt = 0; mt < 8; ++mt) {
      int c0 = mt * 16 + g * 4;
      unsigned xa = x2p[2*mt], xb = x2p[2*mt+1];
      float4 s4 = *(const float4*)(ln_m_s + c0);
      float4 b4 = *(const float4*)(ln_m_b + c0);
      uint2 w2;
      w2.x = cvt_pk_bf16((bf2f((unsigned short)(xa & 0xffff)) - mu) * rs * s4.x + b4.x,
                         (bf2f((unsigned short)(xa >> 16))    - mu) * rs * s4.y + b4.y);
      w2.y = cvt_pk_bf16((bf2f((unsigned short)(xb & 0xffff)) - mu) * rs * s4.z + b4.z,
                         (bf2f((unsigned short)(xb >> 16))    - mu) * rs * s4.w + b4.w);
      *(uint2*)(X + swz(lo, c0)) = w2;
    }
  }
  wave_sync();

  // h1 = y2 @ Wm + bm            (mat 3)
  mmReg<0>(X, wfrag + 3 * 16384, bm, nullptr, nullptr, nullptr, nullptr, nullptr, lo, g, l);
  wave_sync();
  // g1 = gelu(h1 @ W1 + b1)      (mat 4)
  mmReg<1>(X, wfrag + 4 * 16384, b1, nullptr, nullptr, nullptr, nullptr, nullptr, lo, g, l);
  wave_sync();
  // m = g1 @ W2 + b2; out = x2 + gmlp*m   (mat 5)
  mmReg<3>(X, wfrag + 5 * 16384, b2, nullptr, nullptr, x2p, gmlp, outw, lo, g, l);
}

// ---------------------------------------------------------------------------
extern "C" void kernel_launch(void* const* d_in, const int* in_sizes, int n_in,
                              void* d_out, int out_size, void* d_ws, size_t ws_size,
                              hipStream_t stream) {
  const float* x_q     = (const float*)d_in[0];
  const float* x_kv    = (const float*)d_in[1];
  const int* nh_idx    = (const int*)d_in[2];
  const unsigned char* nh_mask = (const unsigned char*)d_in[3];
  const float* ln_q_s  = (const float*)d_in[4];
  const float* ln_q_b  = (const float*)d_in[5];
  const float* Wq      = (const float*)d_in[6];
  const float* bq      = (const float*)d_in[7];
  const float* ln_kv_s = (const float*)d_in[8];
  const float* ln_kv_b = (const float*)d_in[9];
  const float* Wkv     = (const float*)d_in[10];
  const float* bkv     = (const float*)d_in[11];
  const float* Wa_q    = (const float*)d_in[12];
  const float* W_out   = (const float*)d_in[13];
  const float* b_out   = (const float*)d_in[14];
  const float* gamma   = (const float*)d_in[15];
  const float* ln_m_s  = (const float*)d_in[16];
  const float* ln_m_b  = (const float*)d_in[17];
  const float* Wm      = (const float*)d_in[18];
  const float* bm      = (const float*)d_in[19];
  const float* W1      = (const float*)d_in[20];
  const float* b1      = (const float*)d_in[21];
  const float* W2      = (const float*)d_in[22];
  const float* b2      = (const float*)d_in[23];
  const float* gmlp    = (const float*)d_in[24];

  unsigned short* wfrag = (unsigned short*)d_ws;          // 192 KB bf16 A-frags
  unsigned short* kvws  = wfrag + 6 * 16384;              // 12.6 MB bf16 kv

  prep_weights<<<384, 256, 0, stream>>>(Wq, Wa_q, W_out, Wm, W1, W2, wfrag);
  kv_proj<<<1536, 256, 0, stream>>>(x_kv, ln_kv_s, ln_kv_b, Wkv, bkv, kvws);
  fused_main<<<6144, 256, 0, stream>>>(
      x_q, nh_idx, nh_mask, wfrag, kvws, ln_q_s, ln_q_b, bq, b_out, gamma,
      ln_m_s, ln_m_b, bm, b1, b2, gmlp, (float*)d_out);
}

// Round 17
// 345.149 us; speedup vs baseline: 1.1358x; 1.1358x over previous
//
#include <hip/hip_runtime.h>
#include <hip/hip_bf16.h>

#define DEVINL __device__ __forceinline__

typedef __attribute__((ext_vector_type(8))) short bf16x8;
typedef __attribute__((ext_vector_type(4))) float f32x4;

static constexpr int SS = 12288;   // S = NKV
static constexpr float QKS = 0.17677669529663687f;  // 1/sqrt(32), folded into Wa_q

DEVINL f32x4 f32x4_zero() { f32x4 z; z[0]=0.f; z[1]=0.f; z[2]=0.f; z[3]=0.f; return z; }
DEVINL f32x4 mfma16(bf16x8 a, bf16x8 b, f32x4 c) {
  return __builtin_amdgcn_mfma_f32_16x16x32_bf16(a, b, c, 0, 0, 0);
}
DEVINL unsigned short f2bf(float f) {   // prep kernels only
  __hip_bfloat16 h = __float2bfloat16(f);
  return __builtin_bit_cast(unsigned short, h);
}
DEVINL float bf2f(unsigned short u) {
  unsigned v = ((unsigned)u) << 16;
  return __builtin_bit_cast(float, v);
}
DEVINL unsigned cvt_pk_bf16(float lo_, float hi_) {  // [15:0]=lo_, [31:16]=hi_
  unsigned r;
  asm volatile("v_cvt_pk_bf16_f32 %0, %1, %2" : "=v"(r) : "v"(lo_), "v"(hi_));
  return r;
}
// 8-way XOR-swizzled element offset into a [16][128] bf16 LDS tile (R5/R9-proven)
DEVINL int swz(int r, int c) {
  return (r << 7) + ((((c >> 3) ^ (r & 7))) << 3) + (c & 7);
}
DEVINL void wave_sync() {
  asm volatile("s_waitcnt lgkmcnt(0)" ::: "memory");
  __builtin_amdgcn_sched_barrier(0);
}
DEVINL float gelu_f(float x) {  // tanh-approximate gelu (jax default)
  float u = 0.7978845608028654f * (x + 0.044715f * x * x * x);
  float t = 1.0f - 2.0f / (__expf(2.0f * u) + 1.0f);
  return 0.5f * x * (1.0f + t);
}

// stage one 8 KB weight slice (one kt of one matmul) -> LDS slot (= 2 VMEM ops)
DEVINL void stage8(const unsigned short* __restrict__ wf_all,
                   unsigned short* slot, int slice, int tid) {
  const unsigned short* src = wf_all + (size_t)slice * 4096;
  const int wv = tid >> 6, l = tid & 63;
#pragma unroll
  for (int r = 0; r < 2; ++r) {
    int off = (r * 4 + wv) * 512;   // ush; wave-uniform base, HW adds lane*16B
    __builtin_amdgcn_global_load_lds(
        (const __attribute__((address_space(1))) unsigned int*)(src + off + l * 8),
        (__attribute__((address_space(3))) unsigned int*)(slot + off), 16, 0, 0);
  }
}

// ---------------------------------------------------------------------------
// Kernel 0: repack six 128x128 fp32 weights into bf16 MFMA A-fragment order
// (A = W^T). slice j = mat*4+kt; elem (j, mt, l, i) holds
// W[kt*32+(l>>4)*8+i][mt*16+(l&15)]  (Wa_q pre-scaled by QKS).
// ---------------------------------------------------------------------------
__global__ void prep_weights(const float* __restrict__ w0, const float* __restrict__ w1,
                             const float* __restrict__ w2, const float* __restrict__ w3,
                             const float* __restrict__ w4, const float* __restrict__ w5,
                             unsigned short* __restrict__ wfrag) {
  int gid = blockIdx.x * 256 + threadIdx.x;   // < 98304
  int i  = gid & 7;
  int l  = (gid >> 3) & 63;
  int mt = (gid >> 9) & 7;
  int kt = (gid >> 12) & 3;
  int mat = gid >> 14;
  const float* W = (mat == 0) ? w0 : (mat == 1) ? w1 : (mat == 2) ? w2
                 : (mat == 3) ? w3 : (mat == 4) ? w4 : w5;
  int k = kt * 32 + (l >> 4) * 8 + i;
  int c = mt * 16 + (l & 15);
  float v = W[k * 128 + c];
  if (mat == 1) v *= QKS;
  wfrag[gid] = f2bf(v);
}

// ---------------------------------------------------------------------------
// Kernel 1: kv = LN(x_kv) @ Wkv + bkv -> bf16 workspace [24576][256]  (R9)
// ---------------------------------------------------------------------------
__global__ __launch_bounds__(256) void kv_proj(
    const float* __restrict__ xkv, const float* __restrict__ lns,
    const float* __restrict__ lnb, const float* __restrict__ Wkv,
    const float* __restrict__ bkv, unsigned short* __restrict__ kvout) {
  __shared__ float y[16][132];
  const int tid = threadIdx.x;
  const size_t rb = (size_t)blockIdx.x * 16;
  {
    int r = tid >> 4, p = tid & 15;
    const float* xr = xkv + (rb + r) * 128 + p * 8;
    float v[8];
    float sum = 0.f, sq = 0.f;
#pragma unroll
    for (int i = 0; i < 2; ++i) {
      float4 q4 = *(const float4*)(xr + i * 4);
      v[i*4+0]=q4.x; v[i*4+1]=q4.y; v[i*4+2]=q4.z; v[i*4+3]=q4.w;
      sum += q4.x + q4.y + q4.z + q4.w;
      sq  += q4.x*q4.x + q4.y*q4.y + q4.z*q4.z + q4.w*q4.w;
    }
    sum += __shfl_xor(sum, 1, 16); sum += __shfl_xor(sum, 2, 16);
    sum += __shfl_xor(sum, 4, 16); sum += __shfl_xor(sum, 8, 16);
    sq  += __shfl_xor(sq, 1, 16);  sq  += __shfl_xor(sq, 2, 16);
    sq  += __shfl_xor(sq, 4, 16);  sq  += __shfl_xor(sq, 8, 16);
    float mu = sum * (1.0f/128.f);
    float rs = rsqrtf(sq * (1.0f/128.f) - mu*mu + 1e-5f);
#pragma unroll
    for (int i = 0; i < 8; ++i) {
      int c = p * 8 + i;
      y[r][c] = (v[i] - mu) * rs * lns[c] + lnb[c];
    }
  }
  __syncthreads();
  const int c2 = tid;
  float acc[16];
#pragma unroll
  for (int r = 0; r < 16; ++r) acc[r] = 0.f;
  for (int c = 0; c < 128; c += 4) {
    float w0 = Wkv[(c+0)*256 + c2];
    float w1 = Wkv[(c+1)*256 + c2];
    float w2 = Wkv[(c+2)*256 + c2];
    float w3 = Wkv[(c+3)*256 + c2];
#pragma unroll
    for (int r = 0; r < 16; ++r) {
      float4 yv = *(const float4*)&y[r][c];
      acc[r] += yv.x*w0 + yv.y*w1 + yv.z*w2 + yv.w*w3;
    }
  }
  float bb = bkv[c2];
#pragma unroll
  for (int r = 0; r < 16; ++r)
    kvout[(rb + r) * 256 + c2] = f2bf(acc[r] + bb);
}

// ---------------------------------------------------------------------------
// mmFlip: per-wave flipped 16x128 @ 128x128 (R9-verbatim math). T4 pipeline:
// 3 LDS slots (slice s -> slot s%3), stage slice j+2 at kt start, and each
// phase barrier is s_waitcnt vmcnt(2) + raw s_barrier: the newest stage (j+2,
// 2 VMEM ops) may stay in flight; the needed slice (j+1) is 2-ops older and
// therefore landed. Tail (j+2 >= 24): vmcnt(0). Activations are wave-private
// so no lgkm drain needed at these barriers.
// MODE 0: (+bias) -> X. MODE 1: +bias, gelu -> X.
// MODE 2: x2 = xq + gamma*(acc+bias) -> packed bf16 regs x2p[16].
// MODE 3: m = acc+bias; out = unpack(x2p) + gmlp*m -> global float4.
// ---------------------------------------------------------------------------
template <int MODE>
DEVINL void mmFlip(unsigned short* X, unsigned short (*Wb)[4096],
                   const unsigned short* __restrict__ wf_all, int j0,
                   const float* __restrict__ bias,
                   const float* __restrict__ xqw, const float* __restrict__ gamma,
                   unsigned* x2p, const float* __restrict__ gmlp,
                   float* __restrict__ outw, int tid) {
  const int l = tid & 63, lo = l & 15, g = l >> 4;
  f32x4 acc[8];
#pragma unroll
  for (int mt = 0; mt < 8; ++mt) acc[mt] = f32x4_zero();

#pragma unroll
  for (int kt = 0; kt < 4; ++kt) {
    const int j = j0 + kt;
    if (j + 2 < 24) stage8(wf_all, Wb[(j + 2) % 3], j + 2, tid);
    const unsigned short* W = Wb[j % 3];
    bf16x8 b = *(const bf16x8*)(X + swz(lo, kt * 32 + g * 8));
#pragma unroll
    for (int mt = 0; mt < 8; ++mt) {
      bf16x8 a = *(const bf16x8*)(W + (mt * 64 + l) * 8);
      acc[mt] = mfma16(a, b, acc[mt]);
    }
    // T4 counted-vmcnt barrier: slice j+1 (needed next) is guaranteed landed.
    if (j + 2 < 24) {
      asm volatile("s_waitcnt vmcnt(2)" ::: "memory");
    } else {
      asm volatile("s_waitcnt vmcnt(0)" ::: "memory");
    }
    __builtin_amdgcn_s_barrier();
    __builtin_amdgcn_sched_barrier(0);
  }

#pragma unroll
  for (int mt = 0; mt < 8; ++mt) {
    int c0 = mt * 16 + g * 4;
    float v0 = acc[mt][0], v1 = acc[mt][1], v2 = acc[mt][2], v3 = acc[mt][3];
    if (bias) {
      float4 b4 = *(const float4*)(bias + c0);
      v0 += b4.x; v1 += b4.y; v2 += b4.z; v3 += b4.w;
    }
    if (MODE == 1) { v0 = gelu_f(v0); v1 = gelu_f(v1); v2 = gelu_f(v2); v3 = gelu_f(v3); }
    if (MODE == 2) {
      float4 x4 = *(const float4*)(xqw + lo * 128 + c0);
      float4 g4 = *(const float4*)(gamma + c0);
      v0 = x4.x + g4.x * v0; v1 = x4.y + g4.y * v1;
      v2 = x4.z + g4.z * v2; v3 = x4.w + g4.w * v3;
      x2p[2 * mt]     = cvt_pk_bf16(v0, v1);
      x2p[2 * mt + 1] = cvt_pk_bf16(v2, v3);
    } else if (MODE == 3) {
      float4 p4 = *(const float4*)(gmlp + c0);
      unsigned xa = x2p[2 * mt], xb = x2p[2 * mt + 1];
      float4 o;
      o.x = bf2f((unsigned short)(xa & 0xffff))  + p4.x * v0;
      o.y = bf2f((unsigned short)(xa >> 16))     + p4.y * v1;
      o.z = bf2f((unsigned short)(xb & 0xffff))  + p4.z * v2;
      o.w = bf2f((unsigned short)(xb >> 16))     + p4.w * v3;
      *(float4*)(outw + lo * 128 + c0) = o;
    } else {
      uint2 w2;
      w2.x = cvt_pk_bf16(v0, v1);
      w2.y = cvt_pk_bf16(v2, v3);
      *(uint2*)(X + swz(lo, c0)) = w2;
    }
  }
}

// ---------------------------------------------------------------------------
// Kernel 2: fused main (R9-verbatim math). Block = 4 waves x 1 s-unit; 8 KB
// weight slices TRIPLE-buffered (24 KB) with counted-vmcnt phase barriers;
// per-su LDS 6.25 KB; x2 packed in regs. 49.6 KB -> 3 blocks/CU.
// ---------------------------------------------------------------------------
__global__ __launch_bounds__(256, 3) void fused_main(
    const float* __restrict__ xq, const int* __restrict__ nh_idx,
    const unsigned char* __restrict__ nh_mask,
    const unsigned short* __restrict__ wfrag,
    const unsigned short* __restrict__ kvws,
    const float* __restrict__ ln_q_s, const float* __restrict__ ln_q_b,
    const float* __restrict__ bq, const float* __restrict__ b_out,
    const float* __restrict__ gamma, const float* __restrict__ ln_m_s,
    const float* __restrict__ ln_m_b, const float* __restrict__ bm,
    const float* __restrict__ b1, const float* __restrict__ b2,
    const float* __restrict__ gmlp, float* __restrict__ out) {
  __shared__ __align__(16) unsigned short Wb[3][4096];   // 24 KB slice ring
  __shared__ __align__(16) unsigned short SU[4][3200];   // X 2048 | K 1152 (ush)

  const int tid = threadIdx.x, l = tid & 63, wv = tid >> 6;
  const int lo = l & 15, g = l >> 4;
  // T1: XCD-aware bijective block swizzle (gridDim.x = 6144, 6144 % 8 == 0)
  const int nwg = gridDim.x;
  const int cpx = nwg >> 3;
  const int bid = (blockIdx.x & 7) * cpx + (blockIdx.x >> 3);
  const int su = bid * 4 + wv;                  // < 24576
  const int t = su / SS, s = su - t * SS;
  const float* xqw = xq + (size_t)su * 2048;
  float* outw = out + (size_t)su * 2048;
  unsigned short* X = SU[wv];             // activations [16][128] swz / V overlay
  unsigned short* K = SU[wv] + 2048;      // K rows [9][128] swz

  // ---- P0: stage slices 0 AND 1; score bias; kv gather
  stage8(wfrag, Wb[0], 0, tid);
  stage8(wfrag, Wb[1], 1, tid);
  float sbias[4];
#pragma unroll
  for (int e = 0; e < 4; ++e) {
    int n = g * 4 + e;
    sbias[e] = (n < 9) ? (nh_mask[s * 9 + n] ? 0.0f : -1e9f) : -1e9f;
  }
  uint4 gr[5];
  {
#pragma unroll
    for (int i = 0; i < 5; ++i) {
      int idx = i * 64 + l;               // 288 = 9 rows x 32 chunks of 16 B
      if (idx < 288) {
        int n = idx >> 5, ch = idx & 31;
        int jrow = nh_idx[s * 9 + n];
        gr[i] = *(const uint4*)(kvws + ((size_t)(t * SS + jrow)) * 256 + ch * 8);
      }
    }
#pragma unroll
    for (int i = 0; i < 5; ++i) {         // land K half immediately
      int idx = i * 64 + l;
      if (idx < 288 && (idx & 31) < 16) {
        int n = idx >> 5, ch = idx & 31;
        *(uint4*)(K + n * 128 + ((ch ^ (n & 7)) << 3)) = gr[i];
      }
    }
  }

  // ---- P1: LN1 -> X (flip layout: lane owns row lo, channels mt*16+g*4..+3)
  {
    float4 xv[8];
    float sum = 0.f, sq = 0.f;
#pragma unroll
    for (int mt = 0; mt < 8; ++mt) {
      xv[mt] = *(const float4*)(xqw + lo * 128 + mt * 16 + g * 4);
      sum += xv[mt].x + xv[mt].y + xv[mt].z + xv[mt].w;
      sq  += xv[mt].x*xv[mt].x + xv[mt].y*xv[mt].y + xv[mt].z*xv[mt].z + xv[mt].w*xv[mt].w;
    }
    sum += __shfl_xor(sum, 16); sum += __shfl_xor(sum, 32);
    sq  += __shfl_xor(sq, 16);  sq  += __shfl_xor(sq, 32);
    float mu = sum * (1.0f/128.f);
    float rs = rsqrtf(sq * (1.0f/128.f) - mu*mu + 1e-5f);
#pragma unroll
    for (int mt = 0; mt < 8; ++mt) {
      int c0 = mt * 16 + g * 4;
      float4 s4 = *(const float4*)(ln_q_s + c0);
      float4 b4 = *(const float4*)(ln_q_b + c0);
      uint2 w2;
      w2.x = cvt_pk_bf16((xv[mt].x - mu) * rs * s4.x + b4.x,
                         (xv[mt].y - mu) * rs * s4.y + b4.y);
      w2.y = cvt_pk_bf16((xv[mt].z - mu) * rs * s4.z + b4.z,
                         (xv[mt].w - mu) * rs * s4.w + b4.w);
      *(uint2*)(X + swz(lo, c0)) = w2;
    }
  }
  wave_sync();
  __syncthreads();   // full drain once: slices 0,1 staged; LN/K writes visible

  unsigned x2p[16];

  // q  = y1 @ Wq + bq            slices 0..3
  mmFlip<0>(X, Wb, wfrag, 0, bq, nullptr, nullptr, nullptr, nullptr, nullptr, tid);
  wave_sync();
  // qh = q @ (Wa_q * QKS)        slices 4..7
  mmFlip<0>(X, Wb, wfrag, 4, nullptr, nullptr, nullptr, nullptr, nullptr, nullptr, tid);
  wave_sync();

  // ---- attention (wave-local, MFMA; R9-verbatim) + T5 setprio
  {
    const int krow = (lo > 8) ? 8 : lo;   // clamp; garbage rows killed by sbias
    f32x4 st[4];
    __builtin_amdgcn_s_setprio(1);
#pragma unroll
    for (int h = 0; h < 4; ++h) {
      bf16x8 ka = *(const bf16x8*)(K + swz(krow, h * 32 + g * 8));  // A = K
      bf16x8 qb = *(const bf16x8*)(X + swz(lo,   h * 32 + g * 8));  // B = qh
      st[h] = mfma16(ka, qb, f32x4_zero());                         // St[n][q]
    }
    __builtin_amdgcn_s_setprio(0);
    wave_sync();   // qh reads retired -> X reusable for V
    // land V interleaved into X: [8 nt][8 npair][16 d][2] (stale slots finite)
#pragma unroll
    for (int i = 0; i < 5; ++i) {
      int idx = i * 64 + l;
      if (idx < 288 && (idx & 31) >= 16) {
        int n = idx >> 5, d0 = ((idx & 31) - 16) * 8;
        int nt = d0 >> 4;
        int base = nt * 256 + (n >> 1) * 32 + (d0 & 15) * 2 + (n & 1);
        const unsigned short* u = (const unsigned short*)&gr[i];
#pragma unroll
        for (int dd = 0; dd < 8; ++dd) X[base + dd * 2] = u[dd];
      }
    }
    // softmax over n (in-lane e + shfl over g) and P A-frag assembly
    bf16x8 pfrag[4];
#pragma unroll
    for (int h = 0; h < 4; ++h) {
      float p0 = st[h][0] + sbias[0], p1 = st[h][1] + sbias[1];
      float p2 = st[h][2] + sbias[2], p3 = st[h][3] + sbias[3];
      float m = fmaxf(fmaxf(p0, p1), fmaxf(p2, p3));
      m = fmaxf(m, __shfl_xor(m, 16)); m = fmaxf(m, __shfl_xor(m, 32));
      p0 = __expf(p0 - m); p1 = __expf(p1 - m);
      p2 = __expf(p2 - m); p3 = __expf(p3 - m);
      float ss = p0 + p1 + p2 + p3;
      ss += __shfl_xor(ss, 16); ss += __shfl_xor(ss, 32);
      float inv = 1.0f / ss;
      p0 *= inv; p1 *= inv; p2 *= inv; p3 *= inv;
      // lane needs P[q=lo][n=g*8+i]; own lane holds P[n=g*4+e][q=lo]
      float b0 = __shfl_xor(p0, 16), b1 = __shfl_xor(p1, 16),
            b2_ = __shfl_xor(p2, 16), b3 = __shfl_xor(p3, 16);
      float c0_ = __shfl_xor(p0, 32), c1 = __shfl_xor(p1, 32),
            c2 = __shfl_xor(p2, 32), c3 = __shfl_xor(p3, 32);
      float d0_ = __shfl_xor(p0, 48), d1 = __shfl_xor(p1, 48),
            d2 = __shfl_xor(p2, 48), d3 = __shfl_xor(p3, 48);
      float L0 = (g == 0) ? p0 : (g == 1) ? d0_ : 0.f;
      float L1 = (g == 0) ? p1 : (g == 1) ? d1 : 0.f;
      float L2 = (g == 0) ? p2 : (g == 1) ? d2 : 0.f;
      float L3 = (g == 0) ? p3 : (g == 1) ? d3 : 0.f;
      float H0 = (g == 0) ? b0 : (g == 1) ? c0_ : 0.f;
      float H1 = (g == 0) ? b1 : (g == 1) ? c1 : 0.f;
      float H2 = (g == 0) ? b2_ : (g == 1) ? c2 : 0.f;
      float H3 = (g == 0) ? b3 : (g == 1) ? c3 : 0.f;
      uint4 pu;
      pu.x = cvt_pk_bf16(L0, L1); pu.y = cvt_pk_bf16(L2, L3);
      pu.z = cvt_pk_bf16(H0, H1); pu.w = cvt_pk_bf16(H2, H3);
      pfrag[h] = __builtin_bit_cast(bf16x8, pu);
    }
    wave_sync();   // V writes landed
    // PV: out[q][d] = P @ V; B-frag = 4x ds_read_b32 (g<2 hold n=0..15)
    f32x4 oacc[8];
    __builtin_amdgcn_s_setprio(1);
#pragma unroll
    for (int nt = 0; nt < 8; ++nt) {
      unsigned vw0 = 0, vw1 = 0, vw2 = 0, vw3 = 0;
      if (g < 2) {
        const unsigned short* vb = X + nt * 256 + g * 128 + lo * 2;
        vw0 = *(const unsigned*)(vb);
        vw1 = *(const unsigned*)(vb + 32);
        vw2 = *(const unsigned*)(vb + 64);
        vw3 = *(const unsigned*)(vb + 96);
      }
      uint4 vu; vu.x = vw0; vu.y = vw1; vu.z = vw2; vu.w = vw3;
      bf16x8 vfrag = __builtin_bit_cast(bf16x8, vu);
      oacc[nt] = mfma16(pfrag[nt >> 1], vfrag, f32x4_zero());
    }
    __builtin_amdgcn_s_setprio(0);
    wave_sync();   // V reads done -> overwrite X with ao (full coverage)
#pragma unroll
    for (int nt = 0; nt < 8; ++nt)
#pragma unroll
      for (int e = 0; e < 4; ++e)
        X[swz(g * 4 + e, nt * 16 + lo)] = (unsigned short)(cvt_pk_bf16(oacc[nt][e], 0.f) & 0xffff);
    wave_sync();
  }

  // x2 = xq + gamma*(ao @ W_out + b_out) -> x2p regs   slices 8..11
  mmFlip<2>(X, Wb, wfrag, 8, b_out, xqw, gamma, x2p, nullptr, nullptr, tid);

  // ---- LN2 from x2p -> y2 -> X (lane owns full row lo)
  {
    float sum = 0.f, sq = 0.f;
#pragma unroll
    for (int mt = 0; mt < 8; ++mt) {
      unsigned xa = x2p[2*mt], xb = x2p[2*mt+1];
      float v0 = bf2f((unsigned short)(xa & 0xffff));
      float v1 = bf2f((unsigned short)(xa >> 16));
      float v2 = bf2f((unsigned short)(xb & 0xffff));
      float v3 = bf2f((unsigned short)(xb >> 16));
      sum += v0 + v1 + v2 + v3;
      sq  += v0*v0 + v1*v1 + v2*v2 + v3*v3;
    }
    sum += __shfl_xor(sum, 16); sum += __shfl_xor(sum, 32);
    sq  += __shfl_xor(sq, 16);  sq  += __shfl_xor(sq, 32);
    float mu = sum * (1.0f/128.f);
    float rs = rsqrtf(sq * (1.0f/128.f) - mu*mu + 1e-5f);
#pragma unroll
    for (int mt = 0; mt < 8; ++mt) {
      int c0 = mt * 16 + g * 4;
      unsigned xa = x2p[2*mt], xb = x2p[2*mt+1];
      float4 s4 = *(const float4*)(ln_m_s + c0);
      float4 b4 = *(const float4*)(ln_m_b + c0);
      uint2 w2;
      w2.x = cvt_pk_bf16((bf2f((unsigned short)(xa & 0xffff)) - mu) * rs * s4.x + b4.x,
                         (bf2f((unsigned short)(xa >> 16))    - mu) * rs * s4.y + b4.y);
      w2.y = cvt_pk_bf16((bf2f((unsigned short)(xb & 0xffff)) - mu) * rs * s4.z + b4.z,
                         (bf2f((unsigned short)(xb >> 16))    - mu) * rs * s4.w + b4.w);
      *(uint2*)(X + swz(lo, c0)) = w2;
    }
  }
  wave_sync();

  // h1 = y2 @ Wm + bm            slices 12..15
  mmFlip<0>(X, Wb, wfrag, 12, bm, nullptr, nullptr, nullptr, nullptr, nullptr, tid);
  wave_sync();
  // g1 = gelu(h1 @ W1 + b1)      slices 16..19
  mmFlip<1>(X, Wb, wfrag, 16, b1, nullptr, nullptr, nullptr, nullptr, nullptr, tid);
  wave_sync();
  // m = g1 @ W2 + b2; out = x2 + gmlp*m   slices 20..23
  mmFlip<3>(X, Wb, wfrag, 20, b2, nullptr, nullptr, x2p, gmlp, outw, tid);
}

// ---------------------------------------------------------------------------
extern "C" void kernel_launch(void* const* d_in, const int* in_sizes, int n_in,
                              void* d_out, int out_size, void* d_ws, size_t ws_size,
                              hipStream_t stream) {
  const float* x_q     = (const float*)d_in[0];
  const float* x_kv    = (const float*)d_in[1];
  const int* nh_idx    = (const int*)d_in[2];
  const unsigned char* nh_mask = (const unsigned char*)d_in[3];
  const float* ln_q_s  = (const float*)d_in[4];
  const float* ln_q_b  = (const float*)d_in[5];
  const float* Wq      = (const float*)d_in[6];
  const float* bq      = (const float*)d_in[7];
  const float* ln_kv_s = (const float*)d_in[8];
  const float* ln_kv_b = (const float*)d_in[9];
  const float* Wkv     = (const float*)d_in[10];
  const float* bkv     = (const float*)d_in[11];
  const float* Wa_q    = (const float*)d_in[12];
  const float* W_out   = (const float*)d_in[13];
  const float* b_out   = (const float*)d_in[14];
  const float* gamma   = (const float*)d_in[15];
  const float* ln_m_s  = (const float*)d_in[16];
  const float* ln_m_b  = (const float*)d_in[17];
  const float* Wm      = (const float*)d_in[18];
  const float* bm      = (const float*)d_in[19];
  const float* W1      = (const float*)d_in[20];
  const float* b1      = (const float*)d_in[21];
  const float* W2      = (const float*)d_in[22];
  const float* b2      = (const float*)d_in[23];
  const float* gmlp    = (const float*)d_in[24];

  unsigned short* wfrag = (unsigned short*)d_ws;          // 192 KB bf16 A-frags
  unsigned short* kvws  = wfrag + 6 * 16384;              // 12.6 MB bf16 kv

  prep_weights<<<384, 256, 0, stream>>>(Wq, Wa_q, W_out, Wm, W1, W2, wfrag);
  kv_proj<<<1536, 256, 0, stream>>>(x_kv, ln_kv_s, ln_kv_b, Wkv, bkv, kvws);
  fused_main<<<6144, 256, 0, stream>>>(
      x_q, nh_idx, nh_mask, wfrag, kvws, ln_q_s, ln_q_b, bq, b_out, gamma,
      ln_m_s, ln_m_b, bm, b1, b2, gmlp, (float*)d_out);
}